// Round 1
// baseline (1376.354 us; speedup 1.0000x reference)
//
#include <hip/hip_runtime.h>
#include <hip/hip_bf16.h>

#define NQ 14
#define DIM 16384          // 2^14
#define HALF_DIM 8192
#define QDIM 4096
#define BLOCK 1024
#define NWAVES (BLOCK / 64)

// One workgroup = one batch element. Full complex64 state in LDS (128 KB of
// the 160 KB/CU on gfx950). 2 layers of (14 RY + 13 CNOT) applied in-place
// with a barrier per gate; epilogue computes all 14 Z-expectations in one
// pass with wave-shuffle + cross-wave LDS reduction.
__global__ __launch_bounds__(BLOCK) void qsim_kernel(
    const void* __restrict__ xraw,    // (B, 14) angles, bf16 or f32
    const void* __restrict__ praw,    // (28,)   shared RY angles
    void* __restrict__ outraw)        // (B, 14) Z expectations
{
    __shared__ float sRe[DIM];
    __shared__ float sIm[DIM];
    __shared__ float cx[NQ], sx[NQ];        // encoding cos/sin (per batch elt)
    __shared__ float cg[2 * NQ], sg[2 * NQ];// gate cos/sin (shared params)
    __shared__ float red[NWAVES][NQ];
    __shared__ int sflag;

    const int b = blockIdx.x;
    const int tid = threadIdx.x;

    // ---- dtype sniff: view x as bf16 halfwords. If the buffer is really
    // float32, every other halfword is low-mantissa noise with a uniform
    // exponent field -> many "wild" bf16 exponents. bf16 N(0,1) data has
    // exponents confined near the bias. Data-stationary -> same result
    // every call (graph-safe).
    if (tid == 0) {
        const unsigned short* h = (const unsigned short*)xraw;
        int ev = 0;
        for (int k = 0; k < 64; ++k) {
            unsigned short v = h[k];
            int e = (v >> 7) & 0xFF;
            if (e == 0xFF || e > 140 || (e != 0 && e < 110)) ev++;
        }
        sflag = (ev < 8) ? 1 : 0;   // 1 => bf16 buffers
    }
    __syncthreads();
    const int isbf = sflag;

    if (tid < NQ) {
        float xv = isbf ? (float)((const __hip_bfloat16*)xraw)[b * NQ + tid]
                        : ((const float*)xraw)[b * NQ + tid];
        float a = 0.5f * xv;
        cx[tid] = cosf(a);
        sx[tid] = sinf(a);
    } else if (tid >= 64 && tid < 64 + 2 * NQ) {
        int j = tid - 64;
        float pv = isbf ? (float)((const __hip_bfloat16*)praw)[j]
                        : ((const float*)praw)[j];
        float a = 0.5f * pv;
        cg[j] = cosf(a);
        sg[j] = sinf(a);
    }
    __syncthreads();

    // ---- init product state: amp(i) = prod_q (bit ? -i*sin : cos).
    // Each set bit contributes a factor (-i); phase = (-i)^popcount(i).
    for (int i = tid; i < DIM; i += BLOCK) {
        float mag = 1.0f;
        #pragma unroll
        for (int q = 0; q < NQ; ++q) {
            int bit = (i >> (NQ - 1 - q)) & 1;
            mag *= bit ? sx[q] : cx[q];
        }
        int k = __popc(i) & 3;
        sRe[i] = (k == 0) ? mag : ((k == 2) ? -mag : 0.0f);
        sIm[i] = (k == 1) ? -mag : ((k == 3) ? mag : 0.0f);
    }
    __syncthreads();

    for (int layer = 0; layer < 2; ++layer) {
        // ---- RY on each qubit (G = [[c,-s],[s,c]])
        for (int w = 0; w < NQ; ++w) {
            const int m = NQ - 1 - w;           // bit position of qubit w
            const float cw = cg[layer * NQ + w];
            const float sw = sg[layer * NQ + w];
            const int low = (1 << m) - 1;
            for (int p = tid; p < HALF_DIM; p += BLOCK) {
                int i0 = ((p & ~low) << 1) | (p & low);
                int i1 = i0 | (1 << m);
                float a0r = sRe[i0], a0i = sIm[i0];
                float a1r = sRe[i1], a1i = sIm[i1];
                sRe[i0] = cw * a0r - sw * a1r;
                sIm[i0] = cw * a0i - sw * a1i;
                sRe[i1] = sw * a0r + cw * a1r;
                sIm[i1] = sw * a0i + cw * a1i;
            }
            __syncthreads();
        }
        // ---- CNOT chain w -> w+1: swap target bit where control bit == 1
        for (int w = 0; w < NQ - 1; ++w) {
            const int mc = NQ - 1 - w;          // control bit
            const int mt = mc - 1;              // target bit
            const int lowt = (1 << mt) - 1;
            for (int p = tid; p < QDIM; p += BLOCK) {
                int i0 = ((p & ~lowt) << 2) | (1 << mc) | (p & lowt);
                int i1 = i0 | (1 << mt);
                float r0 = sRe[i0], q0 = sIm[i0];
                sRe[i0] = sRe[i1];
                sIm[i0] = sIm[i1];
                sRe[i1] = r0;
                sIm[i1] = q0;
            }
            __syncthreads();
        }
    }

    // ---- Z expectations: out_w = sum_i |a_i|^2 * (bit_w(i) ? -1 : +1)
    float acc[NQ];
    #pragma unroll
    for (int w = 0; w < NQ; ++w) acc[w] = 0.0f;
    for (int i = tid; i < DIM; i += BLOCK) {
        float r = sRe[i], im = sIm[i];
        float p = r * r + im * im;
        #pragma unroll
        for (int w = 0; w < NQ; ++w) {
            acc[w] += ((i >> (NQ - 1 - w)) & 1) ? -p : p;
        }
    }
    #pragma unroll
    for (int w = 0; w < NQ; ++w) {
        float v = acc[w];
        for (int off = 32; off > 0; off >>= 1)
            v += __shfl_down(v, off, 64);
        acc[w] = v;
    }
    const int wave = tid >> 6;
    const int lane = tid & 63;
    if (lane == 0) {
        #pragma unroll
        for (int w = 0; w < NQ; ++w) red[wave][w] = acc[w];
    }
    __syncthreads();
    if (tid < NQ) {
        float v = 0.0f;
        #pragma unroll
        for (int wv = 0; wv < NWAVES; ++wv) v += red[wv][tid];
        if (isbf) {
            ((__hip_bfloat16*)outraw)[b * NQ + tid] = __float2bfloat16(v);
        } else {
            ((float*)outraw)[b * NQ + tid] = v;
        }
    }
}

extern "C" void kernel_launch(void* const* d_in, const int* in_sizes, int n_in,
                              void* d_out, int out_size, void* d_ws, size_t ws_size,
                              hipStream_t stream) {
    const void* x = d_in[0];
    const void* params = d_in[1];
    const int B = in_sizes[0] / NQ;   // 4096
    qsim_kernel<<<B, BLOCK, 0, stream>>>(x, params, d_out);
}

// Round 2
// 75.536 us; speedup vs baseline: 18.2213x; 18.2213x over previous
//
#include <hip/hip_runtime.h>
#include <hip/hip_bf16.h>

#define NQ 14
#define BLOCK 64
#define ELEMS_PER_BLOCK (BLOCK / 8)   // 8 lanes per batch element

// Transfer-matrix contraction of the QuantumGate circuit.
//
// Key identity: the adjacent CNOT chain (w -> w+1, applied sequentially) is a
// classical permutation of basis states: c = prefixXOR(b). So
//   psi = P . RY2 . P . (RY1 . RX)|0>
// and
//   psi(e) = sum_d  prod_q  G_q[e_q^e_{q-1}, d_q] * u_q[d_q^d_{q-1}]
// where u_q = RY(p0_q) RX(x_q)|0> (complex 2-vec) and G_q = RY(p1_q) (real 2x2).
// <Z_w> = sum_e (1-2 e_w)|psi(e)|^2 contracts as a chain over the joint bond
// state s = (e,d,d') in {0,1}^3 (8 states) with complex 8x8 transfer matrices
//   T_q[s,s'] = M_q[e^e', d, d'] * conj(M_q[e^e', dp, dp']),
//   M_q[f, dn, do] = G_q[f][dn] * u_q[dn^do].
// Forward pass L^(q+1) = T_q L^(q) (L^(0)=delta_0), history kept in registers;
// backward pass R^(q-1) = R^(q) T_q with R^(13) = 1^T, and since the Z at site
// w is diagonal in the destination e:  <Z_w> = Re sum_s sign(e_s) L^(w+1)[s] R^(w)[s].
//
// One bond-state component per lane (8 lanes/element); cross-lane all-gather
// via __shfl (ds_bpermute). No LDS state, no barriers.

typedef float2 cplx;
__device__ __forceinline__ cplx cmul(cplx a, cplx b) {
    return make_float2(a.x * b.x - a.y * b.y, a.x * b.y + a.y * b.x);
}
__device__ __forceinline__ cplx cmadd(cplx acc, cplx a, cplx b) {
    return make_float2(acc.x + a.x * b.x - a.y * b.y,
                       acc.y + a.x * b.y + a.y * b.x);
}
__device__ __forceinline__ cplx conjc(cplx a) { return make_float2(a.x, -a.y); }
__device__ __forceinline__ cplx cscale(float s, cplx a) { return make_float2(s * a.x, s * a.y); }

__global__ __launch_bounds__(BLOCK) void qsim_tm(const void* __restrict__ xraw,
                                                 const void* __restrict__ praw,
                                                 void* __restrict__ outraw)
{
    const int tid  = threadIdx.x;
    const int lane = tid & 63;
    const int s    = lane & 7;        // bond state (e<<2)|(d<<1)|dp
    const int g8   = lane & ~7;       // group base lane
    const int e  = (s >> 2) & 1;
    const int d  = (s >> 1) & 1;
    const int dp = s & 1;
    const int b  = blockIdx.x * ELEMS_PER_BLOCK + (tid >> 3);

    // ---- dtype sniff (identical logic to the round-1 validated kernel).
    // Data-stationary -> same result every call (graph-safe).
    const unsigned short* hw = (const unsigned short*)xraw;
    int ev = 0;
    for (int k = 0; k < 64; ++k) {
        unsigned short v = hw[k];
        int ex = (v >> 7) & 0xFF;
        if (ex == 0xFF || ex > 140 || (ex != 0 && ex < 110)) ev++;
    }
    const int isbf = (ev < 8) ? 1 : 0;

    // ---- per-site data: G_q (real 2x2 via c1,s1) and u_q (complex 2-vec)
    float c1a[NQ], s1a[NQ];
    cplx u0[NQ], u1[NQ];
    #pragma unroll
    for (int q = 0; q < NQ; ++q) {
        float p0, p1, xq;
        if (isbf) {
            p0 = (float)((const __hip_bfloat16*)praw)[q];
            p1 = (float)((const __hip_bfloat16*)praw)[NQ + q];
            xq = (float)((const __hip_bfloat16*)xraw)[b * NQ + q];
        } else {
            p0 = ((const float*)praw)[q];
            p1 = ((const float*)praw)[NQ + q];
            xq = ((const float*)xraw)[b * NQ + q];
        }
        float c0 = cosf(0.5f * p0), s0 = sinf(0.5f * p0);
        c1a[q] = cosf(0.5f * p1);
        s1a[q] = sinf(0.5f * p1);
        float rc = cosf(0.5f * xq), rs = sinf(0.5f * xq);
        // u = RY(p0) . [rc, -i rs]
        u0[q] = make_float2(c0 * rc,  s0 * rs);
        u1[q] = make_float2(s0 * rc, -c0 * rs);
    }

    // ---- forward pass: L^(q+1) = T_q L^(q); hist[q] = L^(q+1)
    cplx L = make_float2((s == 0) ? 1.0f : 0.0f, 0.0f);
    cplx hist[NQ];
    #pragma unroll
    for (int q = 0; q < NQ; ++q) {
        float Lr[8], Li[8];
        #pragma unroll
        for (int sp = 0; sp < 8; ++sp) {
            Lr[sp] = __shfl(L.x, g8 + sp, 64);
            Li[sp] = __shfl(L.y, g8 + sp, 64);
        }
        const float c1 = c1a[q], s1 = s1a[q];
        // G rows: G[0] = (c1, -s1), G[1] = (s1, c1)
        const float gd0 = d  ? -s1 : c1;   // G[0][d]
        const float gd1 = d  ?  c1 : s1;   // G[1][d]
        const float gp0 = dp ? -s1 : c1;   // G[0][dp]
        const float gp1 = dp ?  c1 : s1;   // G[1][dp]
        const cplx ud    = d  ? u1[q] : u0[q];          // u[d]
        const cplx udx   = d  ? u0[q] : u1[q];          // u[d^1]
        const cplx updc  = conjc(dp ? u1[q] : u0[q]);   // conj(u[dp])
        const cplx updxc = conjc(dp ? u0[q] : u1[q]);   // conj(u[dp^1])

        cplx newL = make_float2(0.0f, 0.0f);
        #pragma unroll
        for (int ep = 0; ep < 2; ++ep) {
            const int f = e ^ ep;
            const float gg = (f == 0) ? (gd0 * gp0) : (gd1 * gp1);
            const int base = ep << 2;
            // inner[d'] = conj(u[dp])*L[(ep,d',0)] + conj(u[dp^1])*L[(ep,d',1)]
            cplx in0 = cmadd(cmul(updc, make_float2(Lr[base + 0], Li[base + 0])),
                             updxc, make_float2(Lr[base + 1], Li[base + 1]));
            cplx in1 = cmadd(cmul(updc, make_float2(Lr[base + 2], Li[base + 2])),
                             updxc, make_float2(Lr[base + 3], Li[base + 3]));
            // mid = u[d]*inner[0] + u[d^1]*inner[1]
            cplx mid = cmadd(cmul(ud, in0), udx, in1);
            newL = cmadd(newL, make_float2(gg, 0.0f), mid);
        }
        L = newL;
        hist[q] = L;
    }

    // ---- backward pass: emit <Z_q>, then R <- R T_q
    const float sgn = e ? -1.0f : 1.0f;
    cplx R = make_float2(1.0f, 0.0f);
    #pragma unroll
    for (int qq = 0; qq < NQ; ++qq) {
        const int q = NQ - 1 - qq;
        // <Z_q> = Re sum_s sign(e_s) * hist[q][s] * R[s]
        float t = sgn * (hist[q].x * R.x - hist[q].y * R.y);
        t += __shfl_xor(t, 1, 64);
        t += __shfl_xor(t, 2, 64);
        t += __shfl_xor(t, 4, 64);
        if (s == 0) {
            if (isbf) ((__hip_bfloat16*)outraw)[b * NQ + q] = __float2bfloat16(t);
            else      ((float*)outraw)[b * NQ + q] = t;
        }
        if (qq == NQ - 1) break;

        // transposed matvec: newR[s_lane] = sum_s T_q[s, s_lane] R[s]
        float Rr[8], Ri[8];
        #pragma unroll
        for (int sp = 0; sp < 8; ++sp) {
            Rr[sp] = __shfl(R.x, g8 + sp, 64);
            Ri[sp] = __shfl(R.y, g8 + sp, 64);
        }
        const float c1 = c1a[q], s1 = s1a[q];
        const cplx ud    = d  ? u1[q] : u0[q];          // u[d_lane]
        const cplx udx   = d  ? u0[q] : u1[q];          // u[d_lane^1]
        const cplx updc  = conjc(dp ? u1[q] : u0[q]);   // conj(u[dp_lane])
        const cplx updxc = conjc(dp ? u0[q] : u1[q]);   // conj(u[dp_lane^1])

        cplx newR = make_float2(0.0f, 0.0f);
        #pragma unroll
        for (int es = 0; es < 2; ++es) {
            const int f = es ^ e;
            const float g0 = (f == 0) ? c1 : s1;    // G[f][0]
            const float g1 = (f == 0) ? -s1 : c1;   // G[f][1]
            // coefficient on R[(es, d_src, dp_src)]:
            //   G[f][d_src]*u[d_src^d_lane] * G[f][dp_src]*conj(u[dp_src^dp_lane])
            const cplx cb0 = cscale(g0, updc);
            const cplx cb1 = cscale(g1, updxc);
            const cplx ca0 = cscale(g0, ud);
            const cplx ca1 = cscale(g1, udx);
            const int base = es << 2;
            cplx ib0 = cmadd(cmul(cb0, make_float2(Rr[base + 0], Ri[base + 0])),
                             cb1, make_float2(Rr[base + 1], Ri[base + 1]));
            cplx ib1 = cmadd(cmul(cb0, make_float2(Rr[base + 2], Ri[base + 2])),
                             cb1, make_float2(Rr[base + 3], Ri[base + 3]));
            newR = cmadd(cmadd(newR, ca0, ib0), ca1, ib1);
        }
        R = newR;
    }
}

extern "C" void kernel_launch(void* const* d_in, const int* in_sizes, int n_in,
                              void* d_out, int out_size, void* d_ws, size_t ws_size,
                              hipStream_t stream) {
    const void* x = d_in[0];
    const void* params = d_in[1];
    const int B = in_sizes[0] / NQ;               // 4096
    const int grid = B / ELEMS_PER_BLOCK;         // 512
    qsim_tm<<<grid, BLOCK, 0, stream>>>(x, params, d_out);
}

// Round 3
// 62.093 us; speedup vs baseline: 22.1659x; 1.2165x over previous
//
#include <hip/hip_runtime.h>
#include <hip/hip_bf16.h>

#define NQ 14
#define BLOCK 256
#define EPB (BLOCK / 8)   // 32 batch elements per block, 8 lanes each

// Transfer-matrix contraction of the QuantumGate circuit (see round-2 header
// for the derivation). This revision:
//  - __launch_bounds__(256,1): round-2's 52-VGPR cap spilled hist/u arrays to
//    scratch (WRITE_SIZE 7.4 MB for a 115 KB output). Let the allocator keep
//    ~135 VGPRs live.
//  - Butterfly matvecs: T_q factors over the 3 bond bits (pb, db, eb), so the
//    8x8 matvec is 3 shfl_xor stages; the transposed (backward) matvec carries
//    f=0/1 coefficient variants through stages 1-2 and resolves f at stage 3.
//  - __sinf/__cosf fast intrinsics instead of libm sinf/cosf.
//  - Vectorized sniff + angle loads.

typedef float2 cplx;
__device__ __forceinline__ cplx cmul(cplx a, cplx b) {
    return make_float2(a.x * b.x - a.y * b.y, a.x * b.y + a.y * b.x);
}
// conj(a) * b
__device__ __forceinline__ cplx cconjmul(cplx a, cplx b) {
    return make_float2(a.x * b.x + a.y * b.y, a.x * b.y - a.y * b.x);
}
__device__ __forceinline__ cplx shxor(cplx v, int m) {
    return make_float2(__shfl_xor(v.x, m, 64), __shfl_xor(v.y, m, 64));
}

__global__ __launch_bounds__(BLOCK, 1) void qsim_tm2(const void* __restrict__ xraw,
                                                     const void* __restrict__ praw,
                                                     void* __restrict__ outraw)
{
    const int tid = threadIdx.x;
    const int s   = tid & 7;          // bond state (e<<2)|(d<<1)|p
    const int e   = (s >> 2) & 1;
    const int d   = (s >> 1) & 1;
    const int p   = s & 1;
    const int b   = blockIdx.x * EPB + (tid >> 3);

    // ---- dtype sniff (same discriminator as rounds 1-2, vectorized).
    // 32 halfwords of x viewed as bf16: fp32 N(0,1) data makes the low
    // halfword of each float a wild bf16 exponent (~87% each -> ev ~14);
    // true bf16 data gives ev ~0. Data-stationary -> graph-safe.
    int ev = 0;
    {
        const uint4* sp4 = (const uint4*)xraw;
        uint4 w[4];
        #pragma unroll
        for (int k = 0; k < 4; ++k) w[k] = sp4[k];
        const unsigned* wu = (const unsigned*)w;
        #pragma unroll
        for (int k = 0; k < 8; ++k) {
            unsigned v = wu[k];
            #pragma unroll
            for (int h = 0; h < 2; ++h) {
                int ex = (v >> (7 + 16 * h)) & 0xFF;
                ev += (ex == 0xFF || ex > 140 || (ex != 0 && ex < 110)) ? 1 : 0;
            }
        }
    }
    const bool isbf = (ev < 4);

    // ---- load my element's 14 angles (vectorized) + 28 shared params
    float xang[NQ];
    if (isbf) {
        const unsigned* xu = (const unsigned*)xraw;   // 7 dwords per row
        #pragma unroll
        for (int k = 0; k < 7; ++k) {
            unsigned v = xu[b * 7 + k];
            unsigned lo = (v & 0xFFFFu) << 16;
            unsigned hi = v & 0xFFFF0000u;
            xang[2 * k]     = __uint_as_float(lo);
            xang[2 * k + 1] = __uint_as_float(hi);
        }
    } else {
        const float2* xf = (const float2*)xraw;       // 8B-aligned: 56*b % 8 == 0
        #pragma unroll
        for (int k = 0; k < 7; ++k) {
            float2 v = xf[b * 7 + k];
            xang[2 * k]     = v.x;
            xang[2 * k + 1] = v.y;
        }
    }

    // ---- per-site data: G_q via (c1,s1); u_q = RY(p0) RX(x)|0> (complex 2-vec)
    float c1a[NQ], s1a[NQ];
    cplx u0[NQ], u1[NQ];
    #pragma unroll
    for (int q = 0; q < NQ; ++q) {
        float p0, p1;
        if (isbf) {
            p0 = (float)((const __hip_bfloat16*)praw)[q];
            p1 = (float)((const __hip_bfloat16*)praw)[NQ + q];
        } else {
            p0 = ((const float*)praw)[q];
            p1 = ((const float*)praw)[NQ + q];
        }
        float a0 = 0.5f * p0, a1 = 0.5f * p1, ax = 0.5f * xang[q];
        float c0 = __cosf(a0), s0 = __sinf(a0);
        c1a[q] = __cosf(a1);
        s1a[q] = __sinf(a1);
        float rc = __cosf(ax), rs = __sinf(ax);
        u0[q] = make_float2(c0 * rc,  s0 * rs);
        u1[q] = make_float2(s0 * rc, -c0 * rs);
    }

    // ---- forward: L^(q+1) = T_q L^(q), butterfly over (pb, db, eb)
    cplx L = make_float2((s == 0) ? 1.0f : 0.0f, 0.0f);
    cplx hist[NQ];
    #pragma unroll
    for (int q = 0; q < NQ; ++q) {
        const cplx u0q = u0[q], u1q = u1[q];
        const float c1 = c1a[q], s1 = s1a[q];
        // stage 1 (sum pb): A = conj(u0)*L + conj(u1)*xor1(L)
        cplx Lx = shxor(L, 1);
        cplx A = cconjmul(u0q, L);
        cplx A2 = cconjmul(u1q, Lx);
        A.x += A2.x; A.y += A2.y;
        // stage 2 (sum db): B = u0*A + u1*xor2(A)
        cplx Ax = shxor(A, 2);
        cplx B = cmul(u0q, A);
        cplx B2 = cmul(u1q, Ax);
        B.x += B2.x; B.y += B2.y;
        // stage 3 (sum eb): newL = gg0*B + gg1*xor4(B)
        const float g0d = d ? -s1 : c1, g0p = p ? -s1 : c1;
        const float g1d = d ?  c1 : s1, g1p = p ?  c1 : s1;
        const float gg0 = g0d * g0p, gg1 = g1d * g1p;
        cplx Bx = shxor(B, 4);
        L.x = gg0 * B.x + gg1 * Bx.x;
        L.y = gg0 * B.y + gg1 * Bx.y;
        hist[q] = L;
    }

    // ---- backward: emit <Z_q>, then R <- R^T T_q (transposed butterfly)
    const float sgn = e ? -1.0f : 1.0f;
    cplx R = make_float2(1.0f, 0.0f);
    #pragma unroll
    for (int qq = 0; qq < NQ; ++qq) {
        const int q = NQ - 1 - qq;
        float t = sgn * (hist[q].x * R.x - hist[q].y * R.y);
        t += __shfl_xor(t, 1, 64);
        t += __shfl_xor(t, 2, 64);
        t += __shfl_xor(t, 4, 64);
        if (s == 0) {
            if (isbf) ((__hip_bfloat16*)outraw)[b * NQ + q] = __float2bfloat16(t);
            else      ((float*)outraw)[b * NQ + q] = t;
        }
        if (qq == NQ - 1) break;

        const cplx u0q = u0[q], u1q = u1[q];
        const float c1 = c1a[q], s1 = s1a[q];
        // stage 1 (sum pa): carry f=0/1 variants.
        //   t0 = conj(u0)*R(me), t1 = conj(u1)*R(xor1)
        //   P_f = G[f][p]*t0 + G[f][p^1]*t1
        cplx Rx = shxor(R, 1);
        cplx t0 = cconjmul(u0q, R);
        cplx t1 = cconjmul(u1q, Rx);
        const float gp0 = p ? -s1 : c1, gp0x = p ?  c1 : -s1;
        const float gp1 = p ?  c1 : s1, gp1x = p ?  s1 :  c1;
        cplx P0 = make_float2(gp0 * t0.x + gp0x * t1.x, gp0 * t0.y + gp0x * t1.y);
        cplx P1 = make_float2(gp1 * t0.x + gp1x * t1.x, gp1 * t0.y + gp1x * t1.y);
        // stage 2 (sum da): Q_f = G[f][d]*u0*P_f + G[f][d^1]*u1*xor2(P_f)
        const float gd0 = d ? -s1 : c1, gd0x = d ?  c1 : -s1;
        const float gd1 = d ?  c1 : s1, gd1x = d ?  s1 :  c1;
        cplx P0x = shxor(P0, 2);
        cplx P1x = shxor(P1, 2);
        cplx m0  = cmul(u0q, P0);
        cplx m0x = cmul(u1q, P0x);
        cplx Q0 = make_float2(gd0 * m0.x + gd0x * m0x.x, gd0 * m0.y + gd0x * m0x.y);
        cplx m1  = cmul(u0q, P1);
        cplx m1x = cmul(u1q, P1x);
        cplx Q1 = make_float2(gd1 * m1.x + gd1x * m1x.x, gd1 * m1.y + gd1x * m1x.y);
        // stage 3 (sum ea): Rnew = Q0(me) + xor4(Q1)
        cplx Q1x = shxor(Q1, 4);
        R.x = Q0.x + Q1x.x;
        R.y = Q0.y + Q1x.y;
    }
}

extern "C" void kernel_launch(void* const* d_in, const int* in_sizes, int n_in,
                              void* d_out, int out_size, void* d_ws, size_t ws_size,
                              hipStream_t stream) {
    const void* x = d_in[0];
    const void* params = d_in[1];
    const int B = in_sizes[0] / NQ;          // 4096
    const int grid = (B * 8) / BLOCK;        // 128
    qsim_tm2<<<grid, BLOCK, 0, stream>>>(x, params, d_out);
}

// Round 4
// 61.475 us; speedup vs baseline: 22.3887x; 1.0100x over previous
//
#include <hip/hip_runtime.h>
#include <hip/hip_bf16.h>

#define NQ 14
#define BLOCK 128
#define EPB (BLOCK / 8)   // 16 batch elements per block, 8 lanes each

// Transfer-matrix contraction of the QuantumGate circuit.
//
// Derivation (round 2): the adjacent CNOT chain is a classical basis
// permutation (prefix-XOR), so psi = P.RY2.P.(RY1.RX)|0> and <Z_w> contracts
// as a chain over the joint bond state s=(e,d,p) in {0,1}^3 with 8x8 complex
// transfer matrices that FACTOR over the three bond bits:
//   T[(e,d,p),(e',d',p')] = G[e^e'][d] G[e^e'][p] u[d^d'] conj(u[p^p'])
// One bond-state component per lane (8 lanes/element); each matvec is 3
// shfl_xor butterfly stages. No LDS state, no barriers, no spills
// (__launch_bounds__(BLOCK,1) — round-2's default VGPR cap spilled 7.4 MB).
//
// Round-4 change: 256 blocks x 128 threads so all 256 CUs get one block
// (round 3's 128x256 left half the CUs idle) — this is a floor-probe; the
// timed window is dominated by harness poison fills (84% HBM peak).

typedef float2 cplx;
__device__ __forceinline__ cplx cmul(cplx a, cplx b) {
    return make_float2(a.x * b.x - a.y * b.y, a.x * b.y + a.y * b.x);
}
// conj(a) * b
__device__ __forceinline__ cplx cconjmul(cplx a, cplx b) {
    return make_float2(a.x * b.x + a.y * b.y, a.x * b.y - a.y * b.x);
}
__device__ __forceinline__ cplx shxor(cplx v, int m) {
    return make_float2(__shfl_xor(v.x, m, 64), __shfl_xor(v.y, m, 64));
}

__global__ __launch_bounds__(BLOCK, 1) void qsim_tm3(const void* __restrict__ xraw,
                                                     const void* __restrict__ praw,
                                                     void* __restrict__ outraw)
{
    const int tid = threadIdx.x;
    const int s   = tid & 7;          // bond state (e<<2)|(d<<1)|p
    const int e   = (s >> 2) & 1;
    const int d   = (s >> 1) & 1;
    const int p   = s & 1;
    const int b   = blockIdx.x * EPB + (tid >> 3);

    // ---- dtype sniff (validated rounds 1-3). 32 halfwords of x viewed as
    // bf16: fp32 N(0,1) data makes the low halfword of each float a wild
    // bf16 exponent (ev ~14); true bf16 data gives ev ~0. Data-stationary.
    int ev = 0;
    {
        const uint4* sp4 = (const uint4*)xraw;
        uint4 w[4];
        #pragma unroll
        for (int k = 0; k < 4; ++k) w[k] = sp4[k];
        const unsigned* wu = (const unsigned*)w;
        #pragma unroll
        for (int k = 0; k < 8; ++k) {
            unsigned v = wu[k];
            #pragma unroll
            for (int h = 0; h < 2; ++h) {
                int ex = (v >> (7 + 16 * h)) & 0xFF;
                ev += (ex == 0xFF || ex > 140 || (ex != 0 && ex < 110)) ? 1 : 0;
            }
        }
    }
    const bool isbf = (ev < 4);

    // ---- load my element's 14 angles (vectorized) + 28 shared params
    float xang[NQ];
    if (isbf) {
        const unsigned* xu = (const unsigned*)xraw;   // 7 dwords per row
        #pragma unroll
        for (int k = 0; k < 7; ++k) {
            unsigned v = xu[b * 7 + k];
            xang[2 * k]     = __uint_as_float((v & 0xFFFFu) << 16);
            xang[2 * k + 1] = __uint_as_float(v & 0xFFFF0000u);
        }
    } else {
        const float2* xf = (const float2*)xraw;       // 56*b bytes: 8B-aligned
        #pragma unroll
        for (int k = 0; k < 7; ++k) {
            float2 v = xf[b * 7 + k];
            xang[2 * k]     = v.x;
            xang[2 * k + 1] = v.y;
        }
    }

    // ---- per-site data: G_q via (c1,s1); u_q = RY(p0) RX(x)|0>
    float c1a[NQ], s1a[NQ];
    cplx u0[NQ], u1[NQ];
    #pragma unroll
    for (int q = 0; q < NQ; ++q) {
        float p0, p1;
        if (isbf) {
            p0 = (float)((const __hip_bfloat16*)praw)[q];
            p1 = (float)((const __hip_bfloat16*)praw)[NQ + q];
        } else {
            p0 = ((const float*)praw)[q];
            p1 = ((const float*)praw)[NQ + q];
        }
        float a0 = 0.5f * p0, a1 = 0.5f * p1, ax = 0.5f * xang[q];
        float c0 = __cosf(a0), s0 = __sinf(a0);
        c1a[q] = __cosf(a1);
        s1a[q] = __sinf(a1);
        float rc = __cosf(ax), rs = __sinf(ax);
        u0[q] = make_float2(c0 * rc,  s0 * rs);
        u1[q] = make_float2(s0 * rc, -c0 * rs);
    }

    // ---- forward: L^(q+1) = T_q L^(q), butterfly over (pb, db, eb)
    cplx L = make_float2((s == 0) ? 1.0f : 0.0f, 0.0f);
    cplx hist[NQ];
    #pragma unroll
    for (int q = 0; q < NQ; ++q) {
        const cplx u0q = u0[q], u1q = u1[q];
        const float c1 = c1a[q], s1 = s1a[q];
        // stage 1 (sum p_src): A = conj(u0)*L + conj(u1)*xor1(L)
        cplx Lx = shxor(L, 1);
        cplx A = cconjmul(u0q, L);
        cplx A2 = cconjmul(u1q, Lx);
        A.x += A2.x; A.y += A2.y;
        // stage 2 (sum d_src): B = u0*A + u1*xor2(A)
        cplx Ax = shxor(A, 2);
        cplx B = cmul(u0q, A);
        cplx B2 = cmul(u1q, Ax);
        B.x += B2.x; B.y += B2.y;
        // stage 3 (sum e_src): newL = gg0*B + gg1*xor4(B)
        const float g0d = d ? -s1 : c1, g0p = p ? -s1 : c1;
        const float g1d = d ?  c1 : s1, g1p = p ?  c1 : s1;
        const float gg0 = g0d * g0p, gg1 = g1d * g1p;
        cplx Bx = shxor(B, 4);
        L.x = gg0 * B.x + gg1 * Bx.x;
        L.y = gg0 * B.y + gg1 * Bx.y;
        hist[q] = L;
    }

    // ---- backward: emit <Z_q>, then R <- R^T T_q (transposed butterfly)
    const float sgn = e ? -1.0f : 1.0f;
    cplx R = make_float2(1.0f, 0.0f);
    #pragma unroll
    for (int qq = 0; qq < NQ; ++qq) {
        const int q = NQ - 1 - qq;
        float t = sgn * (hist[q].x * R.x - hist[q].y * R.y);
        t += __shfl_xor(t, 1, 64);
        t += __shfl_xor(t, 2, 64);
        t += __shfl_xor(t, 4, 64);
        if (s == 0) {
            if (isbf) ((__hip_bfloat16*)outraw)[b * NQ + q] = __float2bfloat16(t);
            else      ((float*)outraw)[b * NQ + q] = t;
        }
        if (qq == NQ - 1) break;

        const cplx u0q = u0[q], u1q = u1[q];
        const float c1 = c1a[q], s1 = s1a[q];
        // stage 1 (sum p_src): carry f=0/1 variants (f couples to e at stage 3)
        cplx Rx = shxor(R, 1);
        cplx t0 = cconjmul(u0q, R);
        cplx t1 = cconjmul(u1q, Rx);
        const float gp0 = p ? -s1 : c1, gp0x = p ?  c1 : -s1;
        const float gp1 = p ?  c1 : s1, gp1x = p ?  s1 :  c1;
        cplx P0 = make_float2(gp0 * t0.x + gp0x * t1.x, gp0 * t0.y + gp0x * t1.y);
        cplx P1 = make_float2(gp1 * t0.x + gp1x * t1.x, gp1 * t0.y + gp1x * t1.y);
        // stage 2 (sum d_src)
        const float gd0 = d ? -s1 : c1, gd0x = d ?  c1 : -s1;
        const float gd1 = d ?  c1 : s1, gd1x = d ?  s1 :  c1;
        cplx P0x = shxor(P0, 2);
        cplx P1x = shxor(P1, 2);
        cplx m0  = cmul(u0q, P0);
        cplx m0x = cmul(u1q, P0x);
        cplx Q0 = make_float2(gd0 * m0.x + gd0x * m0x.x, gd0 * m0.y + gd0x * m0x.y);
        cplx m1  = cmul(u0q, P1);
        cplx m1x = cmul(u1q, P1x);
        cplx Q1 = make_float2(gd1 * m1.x + gd1x * m1x.x, gd1 * m1.y + gd1x * m1x.y);
        // stage 3 (sum e_src): Rnew = Q0(me) + xor4(Q1)
        cplx Q1x = shxor(Q1, 4);
        R.x = Q0.x + Q1x.x;
        R.y = Q0.y + Q1x.y;
    }
}

extern "C" void kernel_launch(void* const* d_in, const int* in_sizes, int n_in,
                              void* d_out, int out_size, void* d_ws, size_t ws_size,
                              hipStream_t stream) {
    const void* x = d_in[0];
    const void* params = d_in[1];
    const int B = in_sizes[0] / NQ;          // 4096
    const int grid = (B * 8) / BLOCK;        // 256 -> one block per CU
    qsim_tm3<<<grid, BLOCK, 0, stream>>>(x, params, d_out);
}